// Round 4
// baseline (828.995 us; speedup 1.0000x reference)
//
#include <hip/hip_runtime.h>
#include <hip/hip_bf16.h>

// Fishnet round 4: latency attack on main_kernel.
//  - fixed 128-point ranges per wave (perfect load balance); boundary/first
//    segments flushed with atomicAdd into zeroed Fred/tred
//  - F-phase: 2 points per K=32 MFMA (identical A/B fragment trick) + two
//    alternating accumulators -> dependency chain 16 -> ~4.5
//  - streamed N-tile loop (activation+LDS store immediately per tile) cuts
//    live accumulators 40 -> ~8 regs; __launch_bounds__(256,3)
// Aux: int4 hist/scatter, scan_top+scan_add fused, single memset, seg_kernel
// needs no cnt (zeroed Fred row -> A=I -> theta=0 -> out=0).

#define N_PTS   1000000
#define DIM     64
#define INNER   16
#define OUTD    64
#define NSEG    100000
#define NTRI    136
#define NET_OUT 152
#define NB      391                     // ceil(NSEG/256)
#define RANGE   128
#define NRANGES ((N_PTS + RANGE - 1) / RANGE)    // 7813
#define MAINB   ((NRANGES + 3) / 4)              // 1954
#define N4      (N_PTS / 4)
#define NB4     ((N4 + 255) / 256)               // 977

typedef short bf16x8 __attribute__((ext_vector_type(8)));
typedef float f32x4  __attribute__((ext_vector_type(4)));

__device__ __host__ __forceinline__ constexpr int tri(int i) { return i * (i + 1) / 2; }

__device__ __forceinline__ float fast_tanh(float x) {
    float e = __expf(2.0f * x);
    return 1.0f - __fdividef(2.0f, e + 1.0f);
}
__device__ __forceinline__ float fast_softplus(float x) {
    return __logf(1.0f + __expf(x));
}
__device__ __forceinline__ short f2bf(float f) {   // RNE fp32 -> bf16 bits
    unsigned u = __float_as_uint(f);
    return (short)((u + 0x7FFF + ((u >> 16) & 1)) >> 16);
}

// in-wave LDS producer->consumer ordering (validated rounds 2-3)
__device__ __forceinline__ void wave_lds_sync() {
    __builtin_amdgcn_wave_barrier();
    __builtin_amdgcn_s_waitcnt(0xC07F);   // lgkmcnt(0)
    __builtin_amdgcn_wave_barrier();
}

__device__ __forceinline__ void ecoord(int e, int& r, int& c, bool& dg) {
    int rr = 0;
    #pragma unroll
    for (int k = 1; k < 16; ++k) rr = (e >= tri(k)) ? k : rr;
    r = rr; c = e - tri(rr); dg = (c == rr);
}

// ---------------------------------------------------------------------------
__global__ __launch_bounds__(256) void hist_kernel(const int4* __restrict__ segs4,
                                                   int* __restrict__ cnt,
                                                   int4* __restrict__ rank4)
{
    int t = blockIdx.x * 256 + threadIdx.x;
    if (t < N4) {
        int4 s = segs4[t];
        int4 r;
        r.x = atomicAdd(&cnt[s.x], 1);
        r.y = atomicAdd(&cnt[s.y], 1);
        r.z = atomicAdd(&cnt[s.z], 1);
        r.w = atomicAdd(&cnt[s.w], 1);
        rank4[t] = r;
    }
}

__global__ __launch_bounds__(256) void scan_blocks(const int* __restrict__ cnt,
                                                   int* __restrict__ off,
                                                   int* __restrict__ bsum)
{
    __shared__ int sh[256];
    const int t = threadIdx.x;
    const int i = blockIdx.x * 256 + t;
    int v = (i < NSEG) ? cnt[i] : 0;
    sh[t] = v;
    __syncthreads();
    #pragma unroll
    for (int d = 1; d < 256; d <<= 1) {
        int add = (t >= d) ? sh[t - d] : 0;
        __syncthreads();
        sh[t] += add;
        __syncthreads();
    }
    if (i < NSEG) off[i] = sh[t] - v;
    if (t == 255) bsum[blockIdx.x] = sh[t];
}

// block b adds sum(bsum[0..b-1]) to its 256 off entries (fused top scan)
__global__ __launch_bounds__(256) void scan_addtop(int* __restrict__ off,
                                                   const int* __restrict__ bsum)
{
    __shared__ int sh[256];
    const int t = threadIdx.x;
    const int b = blockIdx.x;
    int part = 0;
    for (int j = t; j < b; j += 256) part += bsum[j];
    sh[t] = part;
    __syncthreads();
    #pragma unroll
    for (int d = 128; d > 0; d >>= 1) {
        if (t < d) sh[t] += sh[t + d];
        __syncthreads();
    }
    int pre = sh[0];
    int i = b * 256 + t;
    if (i < NSEG) off[i] += pre;
}

__global__ __launch_bounds__(256) void scatter_kernel(const int4* __restrict__ segs4,
                                                      const int* __restrict__ off,
                                                      const int4* __restrict__ rank4,
                                                      int* __restrict__ sorted)
{
    int t = blockIdx.x * 256 + threadIdx.x;
    if (t < N4) {
        int4 s = segs4[t];
        int4 r = rank4[t];
        int b = 4 * t;
        sorted[off[s.x] + r.x] = b + 0;
        sorted[off[s.y] + r.y] = b + 1;
        sorted[off[s.z] + r.z] = b + 2;
        sorted[off[s.w] + r.w] = b + 3;
    }
}

// ---------------------------------------------------------------------------
// main: one wave per 128-point range of the sorted order.
// ---------------------------------------------------------------------------
__global__ __launch_bounds__(256, 3)
void main_kernel(const float* __restrict__ data,
                 const int*   __restrict__ segs,
                 const int*   __restrict__ sorted,
                 const float* __restrict__ W,
                 const float* __restrict__ bias,
                 float* __restrict__ Fred,
                 float* __restrict__ tred)
{
    // per wave: 16 point-slots x (16 rows x stride-24 bf16) = 12288 B
    __shared__ __align__(16) unsigned short lds[4 * 6144];
    const int l = threadIdx.x & 63;
    const int w = threadIdx.x >> 6;
    unsigned short* Lw = &lds[w * 6144];
    const int c = l & 15;
    const int q = l >> 4;

    // zero image once: pad cols 16..23 and strict-upper stay zero forever
    #pragma unroll
    for (int u = 0; u < 48; ++u) ((unsigned*)Lw)[u * 64 + l] = 0u;
    wave_lds_sync();

    // W fragments (B-operand layout) + bias
    bf16x8 wf[10][2];
    float  bT[10];
    #pragma unroll
    for (int T = 0; T < 10; ++T) {
        #pragma unroll
        for (int ks = 0; ks < 2; ++ks) {
            bf16x8 f;
            #pragma unroll
            for (int j = 0; j < 8; ++j) {
                int k = 32 * ks + 8 * q + j;
                int n = 16 * T + c;
                f[j] = (n < NET_OUT) ? f2bf(W[k * NET_OUT + n]) : (short)0;
            }
            wf[T][ks] = f;
        }
        int n = 16 * T + c;
        bT[T] = (n < NET_OUT) ? bias[n] : 0.0f;
    }

    // per-lane L-entry coords for T=1..9
    int  rcoff[9];
    bool dgm[9];
    #pragma unroll
    for (int T = 1; T <= 9; ++T) {
        int e = 16 * (T - 1) + c;
        int re, ce; bool dg;
        ecoord(e, re, ce, dg);
        rcoff[T - 1] = re * 24 + ce;
        dgm[T - 1]   = dg;
    }

    int trim[4], mrow[4];
    #pragma unroll
    for (int r = 0; r < 4; ++r) { mrow[r] = 4 * q + r; trim[r] = tri(4 * q + r); }

    const int wave_id = blockIdx.x * 4 + w;
    if (wave_id >= NRANGES) return;
    const int g0 = wave_id * RANGE;
    const int g1 = min(g0 + RANGE, N_PTS);

    f32x4 fa0 = {0.f, 0.f, 0.f, 0.f};
    f32x4 fa1 = {0.f, 0.f, 0.f, 0.f};
    int   par = 0;
    float tcarry = 0.f;
    int   a_start = 0;
    bool  first_flush = true;
    float P0 = 0.f, P1 = 0.f, P2 = 0.f, P3 = 0.f;
    int   ssp = 0;
    unsigned long long bm = 0;

    auto flush = [&](int i, bool atomic_flush) {
        const int sid = __shfl(ssp, i, 64);
        int rs = i & 3;
        float vi = (rs == 0) ? P0 : (rs == 1) ? P1 : (rs == 2) ? P2 : P3;
        float Pi = __shfl(vi, ((i >> 2) << 4) | c, 64);
        float Pe = 0.f;
        if (a_start > 0) {
            int aa = a_start - 1, ra = aa & 3;
            float va = (ra == 0) ? P0 : (ra == 1) ? P1 : (ra == 2) ? P2 : P3;
            Pe = __shfl(va, ((aa >> 2) << 4) | c, 64);
        }
        float ts = Pi - Pe + tcarry;
        f32x4 fs = fa0 + fa1;
        if (atomic_flush) {
            if (l < 16) atomicAdd(&tred[(size_t)sid * INNER + c], ts);
            #pragma unroll
            for (int r = 0; r < 4; ++r)
                if (c <= mrow[r])
                    atomicAdd(&Fred[(size_t)sid * NTRI + trim[r] + c], fs[r]);
        } else {
            if (l < 16) tred[(size_t)sid * INNER + c] = ts;
            #pragma unroll
            for (int r = 0; r < 4; ++r)
                if (c <= mrow[r])
                    Fred[(size_t)sid * NTRI + trim[r] + c] = fs[r];
        }
        tcarry = 0.f;
        fa0 = (f32x4){0.f, 0.f, 0.f, 0.f};
        fa1 = (f32x4){0.f, 0.f, 0.f, 0.f};
        a_start = i + 1;
    };

    for (int g = g0; g < g1; g += 16) {
        const int idx = g + c;
        const int p   = sorted[idx];
        const int pn  = sorted[(idx + 1 < N_PTS) ? idx + 1 : N_PTS - 1];
        ssp = segs[p];
        const int sspn = segs[pn];
        const bool flag = (idx == N_PTS - 1) || (sspn != ssp);
        bm = __ballot(l < 16 && flag);

        // A fragments from gathered data rows
        bf16x8 af0, af1;
        {
            const float4* dp = (const float4*)(data + (size_t)p * DIM + 8 * q);
            float4 x0 = dp[0], x1 = dp[1];
            af0[0] = f2bf(x0.x); af0[1] = f2bf(x0.y); af0[2] = f2bf(x0.z); af0[3] = f2bf(x0.w);
            af0[4] = f2bf(x1.x); af0[5] = f2bf(x1.y); af0[6] = f2bf(x1.z); af0[7] = f2bf(x1.w);
            const float4* dp2 = (const float4*)(data + (size_t)p * DIM + 32 + 8 * q);
            float4 y0 = dp2[0], y1 = dp2[1];
            af1[0] = f2bf(y0.x); af1[1] = f2bf(y0.y); af1[2] = f2bf(y0.z); af1[3] = f2bf(y0.w);
            af1[4] = f2bf(y1.x); af1[5] = f2bf(y1.y); af1[6] = f2bf(y1.z); af1[7] = f2bf(y1.w);
        }

        // T=0 -> t prefix
        {
            f32x4 z = {0.f, 0.f, 0.f, 0.f};
            z = __builtin_amdgcn_mfma_f32_16x16x32_bf16(af0, wf[0][0], z, 0, 0, 0);
            f32x4 a0v = __builtin_amdgcn_mfma_f32_16x16x32_bf16(af1, wf[0][1], z, 0, 0, 0);
            float s0 = a0v[0] + bT[0];
            float s1 = s0 + a0v[1] + bT[0];
            float s2 = s1 + a0v[2] + bT[0];
            float s3 = s2 + a0v[3] + bT[0];
            float v16 = __shfl_up(s3, 16, 64);
            float v32 = __shfl_up(s3, 32, 64);
            float v48 = __shfl_up(s3, 48, 64);
            float excl = (q >= 1 ? v16 : 0.f) + (q >= 2 ? v32 : 0.f) + (q >= 3 ? v48 : 0.f);
            P0 = excl + s0; P1 = excl + s1; P2 = excl + s2; P3 = excl + s3;
        }

        wave_lds_sync();                       // WAR vs previous tile's F reads
        // streamed N-tiles: MFMA -> activate -> store, one T at a time
        #pragma unroll
        for (int T = 1; T <= 9; ++T) {
            f32x4 z = {0.f, 0.f, 0.f, 0.f};
            z = __builtin_amdgcn_mfma_f32_16x16x32_bf16(af0, wf[T][0], z, 0, 0, 0);
            f32x4 aT = __builtin_amdgcn_mfma_f32_16x16x32_bf16(af1, wf[T][1], z, 0, 0, 0);
            #pragma unroll
            for (int r = 0; r < 4; ++r) {
                float v = fast_tanh(aT[r] + bT[T]);
                if (dgm[T - 1]) v = fast_softplus(v);
                if (T < 9 || c < 8)
                    Lw[mrow[r] * 384 + rcoff[T - 1]] = (unsigned short)f2bf(v);
            }
        }
        wave_lds_sync();                       // RAW: writes visible to F reads

        // F phase: pair-packed K=32 MFMAs, dual accumulators
        int i = 0;
        while (i < 16) {
            if ((i < 15) && !((bm >> i) & 1)) {
                bf16x8 lf = *(const bf16x8*)(Lw + (i + (q >> 1)) * 384 + c * 24 + (q & 1) * 8);
                if (par == 0) fa0 = __builtin_amdgcn_mfma_f32_16x16x32_bf16(lf, lf, fa0, 0, 0, 0);
                else          fa1 = __builtin_amdgcn_mfma_f32_16x16x32_bf16(lf, lf, fa1, 0, 0, 0);
                par ^= 1;
                if ((bm >> (i + 1)) & 1) { flush(i + 1, first_flush); first_flush = false; }
                i += 2;
            } else {
                bf16x8 lf = {0, 0, 0, 0, 0, 0, 0, 0};
                if (q < 2)
                    lf = *(const bf16x8*)(Lw + i * 384 + c * 24 + q * 8);
                if (par == 0) fa0 = __builtin_amdgcn_mfma_f32_16x16x32_bf16(lf, lf, fa0, 0, 0, 0);
                else          fa1 = __builtin_amdgcn_mfma_f32_16x16x32_bf16(lf, lf, fa1, 0, 0, 0);
                par ^= 1;
                if ((bm >> i) & 1) { flush(i, first_flush); first_flush = false; }
                i += 1;
            }
        }

        // carry open segment's t partial into next tile
        if (a_start < 16) {
            float Pi = __shfl(P3, 48 | c, 64);
            float Pe = 0.f;
            if (a_start > 0) {
                int aa = a_start - 1, ra = aa & 3;
                float va = (ra == 0) ? P0 : (ra == 1) ? P1 : (ra == 2) ? P2 : P3;
                Pe = __shfl(va, ((aa >> 2) << 4) | c, 64);
            }
            tcarry += Pi - Pe;
        }
        a_start = 0;
    }

    // end-of-range: open segment -> atomic flush
    if (!((bm >> 15) & 1)) {
        const int sid = __shfl(ssp, 15, 64);
        float ts = tcarry;
        f32x4 fs = fa0 + fa1;
        if (l < 16) atomicAdd(&tred[(size_t)sid * INNER + c], ts);
        #pragma unroll
        for (int r = 0; r < 4; ++r)
            if (c <= mrow[r])
                atomicAdd(&Fred[(size_t)sid * NTRI + trim[r] + c], fs[r]);
    }
}

// ---------------------------------------------------------------------------
// seg: per-thread packed Cholesky solve + GEMV (verified). Zeroed Fred row
// (empty segment) -> A=I -> x=1, theta = t_red*1 = 0 -> out = 0. No guard.
// ---------------------------------------------------------------------------
__global__ __launch_bounds__(256, 2)
void seg_kernel(const float* __restrict__ Fred,
                const float* __restrict__ tred,
                const float* __restrict__ projW,
                float* __restrict__ out)
{
    const int s = blockIdx.x * 256 + threadIdx.x;
    if (s >= NSEG) return;

    float a[NTRI];
    const float4* f4 = (const float4*)(Fred + (size_t)s * NTRI);
    #pragma unroll
    for (int qq = 0; qq < NTRI / 4; ++qq) {
        float4 v = f4[qq];
        a[4 * qq + 0] = v.x; a[4 * qq + 1] = v.y;
        a[4 * qq + 2] = v.z; a[4 * qq + 3] = v.w;
    }
    #pragma unroll
    for (int ii = 0; ii < INNER; ++ii) a[tri(ii) + ii] += 1.0f;

    #pragma unroll
    for (int j = 0; j < INNER; ++j) {
        float d = a[tri(j) + j];
        #pragma unroll
        for (int k = 0; k < j; ++k)
            d = fmaf(-a[tri(j) + k], a[tri(j) + k], d);
        d = sqrtf(d);
        a[tri(j) + j] = d;
        float dinv = __fdividef(1.0f, d);
        #pragma unroll
        for (int ii = j + 1; ii < INNER; ++ii) {
            float v = a[tri(ii) + j];
            #pragma unroll
            for (int k = 0; k < j; ++k)
                v = fmaf(-a[tri(ii) + k], a[tri(j) + k], v);
            a[tri(ii) + j] = v * dinv;
        }
    }
    float z[INNER];
    #pragma unroll
    for (int ii = 0; ii < INNER; ++ii) {
        float v = 1.0f;
        #pragma unroll
        for (int k = 0; k < ii; ++k)
            v = fmaf(-a[tri(ii) + k], z[k], v);
        z[ii] = __fdividef(v, a[tri(ii) + ii]);
    }
    float x[INNER];
    #pragma unroll
    for (int ii = INNER - 1; ii >= 0; --ii) {
        float v = z[ii];
        #pragma unroll
        for (int k = ii + 1; k < INNER; ++k)
            v = fmaf(-a[tri(k) + ii], x[k], v);
        x[ii] = __fdividef(v, a[tri(ii) + ii]);
    }
    float theta[INNER];
    const float4* t4 = (const float4*)(tred + (size_t)s * INNER);
    #pragma unroll
    for (int qq = 0; qq < 4; ++qq) {
        float4 v = t4[qq];
        theta[4 * qq + 0] = v.x * x[4 * qq + 0];
        theta[4 * qq + 1] = v.y * x[4 * qq + 1];
        theta[4 * qq + 2] = v.z * x[4 * qq + 2];
        theta[4 * qq + 3] = v.w * x[4 * qq + 3];
    }
    float* orow = out + (size_t)s * OUTD;
    for (int oc = 0; oc < OUTD; oc += 8) {
        float acc[8] = {0, 0, 0, 0, 0, 0, 0, 0};
        #pragma unroll
        for (int j = 0; j < INNER; ++j) {
            float th = theta[j];
            #pragma unroll
            for (int uu = 0; uu < 8; ++uu)
                acc[uu] = fmaf(th, projW[j * OUTD + oc + uu], acc[uu]);
        }
        float4 v0 = {acc[0], acc[1], acc[2], acc[3]};
        float4 v1 = {acc[4], acc[5], acc[6], acc[7]};
        ((float4*)(orow + oc))[0] = v0;
        ((float4*)(orow + oc))[1] = v1;
    }
}

extern "C" void kernel_launch(void* const* d_in, const int* in_sizes, int n_in,
                              void* d_out, int out_size, void* d_ws, size_t ws_size,
                              hipStream_t stream)
{
    const float* data  = (const float*)d_in[0];
    const int*   segs  = (const int*)d_in[1];
    const float* W     = (const float*)d_in[3];
    const float* bias  = (const float*)d_in[4];
    const float* projW = (const float*)d_in[5];

    // [Fred | tred | cnt] contiguous -> single memset
    float* Fred  = (float*)d_ws;                      // NSEG*NTRI
    float* tred  = Fred + (size_t)NSEG * NTRI;        // NSEG*INNER
    int*   cnt   = (int*)(tred + (size_t)NSEG * INNER); // NSEG
    int*   off   = cnt + NSEG;                        // NSEG
    int*   bsum  = off + NSEG;                        // 512
    int*   rank  = bsum + 512;                        // N_PTS
    int*   sorted = rank + N_PTS;                     // N_PTS

    hipMemsetAsync(d_ws, 0, (size_t)NSEG * (NTRI + INNER + 1) * sizeof(float), stream);

    hist_kernel   <<<NB4, 256, 0, stream>>>((const int4*)segs, cnt, (int4*)rank);
    scan_blocks   <<<NB, 256, 0, stream>>>(cnt, off, bsum);
    scan_addtop   <<<NB, 256, 0, stream>>>(off, bsum);
    scatter_kernel<<<NB4, 256, 0, stream>>>((const int4*)segs, off, (const int4*)rank, sorted);
    main_kernel   <<<MAINB, 256, 0, stream>>>(data, segs, sorted, W, bias, Fred, tred);
    seg_kernel    <<<NB, 256, 0, stream>>>(Fred, tred, projW, (float*)d_out);
}